// Round 3
// baseline (6574.677 us; speedup 1.0000x reference)
//
#include <hip/hip_runtime.h>

#define NGRAPH 2048
#define MAXLEN 254
#define NNODE 520192      // NGRAPH * MAXLEN
#define NEDGE 4161536     // NNODE * 8
#define NF 78
#define NBLK 2032         // NNODE / 256
#define BN_EPS 1e-5f
#define LN_EPS 1e-5f

// ---------------- init: zero degree array + total counter
__global__ __launch_bounds__(256) void k_init(int* __restrict__ deg, int* __restrict__ total) {
    int i = blockIdx.x * 256 + threadIdx.x;
    deg[i] = 0;
    if (i == 0) *total = 0;
}

// ---------------- in-degree histogram
__global__ __launch_bounds__(256) void k_hist(const int* __restrict__ ei, int* __restrict__ deg) {
    int e = blockIdx.x * 256 + threadIdx.x;  // NEDGE threads exactly
    atomicAdd(&deg[ei[NEDGE + e]], 1);
}

// ---------------- row offsets: wave-level exclusive scan + one atomic per wave
__global__ __launch_bounds__(256) void k_scan(const int* __restrict__ deg,
                                              int* __restrict__ row_start,
                                              int* __restrict__ cursor, int* __restrict__ total) {
    int i = blockIdx.x * 256 + threadIdx.x;
    int d = deg[i];
    int lane = threadIdx.x & 63;
    int v = d;
#pragma unroll
    for (int o = 1; o < 64; o <<= 1) {
        int t = __shfl_up(v, o, 64);
        if (lane >= o) v += t;
    }
    int wsum = __shfl(v, 63, 64);
    int base = 0;
    if (lane == 63) base = atomicAdd(total, wsum);
    base = __shfl(base, 63, 64);
    int start = base + v - d;
    row_start[i] = start;
    cursor[i] = start;
}

// ---------------- scatter LOCAL src ids (u8) into per-dst contiguous lists
__global__ __launch_bounds__(256) void k_fill(const int* __restrict__ ei, int* __restrict__ cursor,
                                              unsigned char* __restrict__ elist) {
    int e = blockIdx.x * 256 + threadIdx.x;
    int s = ei[e];
    int d = ei[NEDGE + e];
    int g = d / MAXLEN;                       // same graph as src by construction
    int p = atomicAdd(&cursor[d], 1);
    elist[p] = (unsigned char)(s - g * MAXLEN);
}

// ---------------- CSR gather: acc[i] = z[i] + sum_{j->i} z[j]; optionally fold BN affine:
//   acc = agg_z * sc + (1+deg) * bi   where sc/bi derive from raw stats (sum, sumsq)
template <int FOLD>
__global__ __launch_bounds__(256) void k_gather(const float* __restrict__ h,
                                                const unsigned char* __restrict__ elist,
                                                const int* __restrict__ row_start,
                                                const int* __restrict__ deg,
                                                const float* __restrict__ stats,
                                                const float* __restrict__ gamma,
                                                const float* __restrict__ beta,
                                                float* __restrict__ acc) {
    size_t t = (size_t)blockIdx.x * 256 + threadIdx.x;  // NNODE*16 threads
    int node = (int)(t >> 4);
    int g4 = (int)(t & 15) * 4;
    int rs = row_start[node];
    int dg = deg[node];
    int base = (node / MAXLEN) * MAXLEN;                // graph base node id
    const float4 h0 = *(const float4*)(h + ((size_t)node << 6) + g4);
    float a0 = h0.x, a1 = h0.y, a2 = h0.z, a3 = h0.w;
    for (int e = 0; e < dg; e++) {
        int s = base + elist[rs + e];
        float4 v = *(const float4*)(h + ((size_t)s << 6) + g4);
        a0 += v.x; a1 += v.y; a2 += v.z; a3 += v.w;
    }
    if (FOLD) {
        const float invN = 1.0f / NNODE;
        float k = (float)(1 + dg);
        float r[4] = {a0, a1, a2, a3};
#pragma unroll
        for (int j = 0; j < 4; j++) {
            float mean = stats[g4 + j] * invN;
            float var = stats[64 + g4 + j] * invN - mean * mean;
            float sc = gamma[g4 + j] * rsqrtf(var + BN_EPS);
            float bi = beta[g4 + j] - mean * sc;
            r[j] = r[j] * sc + k * bi;
        }
        a0 = r[0]; a1 = r[1]; a2 = r[2]; a3 = r[3];
    }
    *(float4*)(acc + ((size_t)node << 6) + g4) = make_float4(a0, a1, a2, a3);
}

// ---------------- layer-1 first GEMM: t = x @ w1a (N x 78 @ 78 x 64)
__global__ __launch_bounds__(256) void k_gemm78(const float* __restrict__ x,
                                                const float* __restrict__ W,
                                                float* __restrict__ out) {
    __shared__ float sW[NF * 64];
    for (int i = threadIdx.x; i < NF * 64; i += 256) sW[i] = W[i];
    __syncthreads();
    int node = blockIdx.x * 256 + threadIdx.x;  // N divisible by 256
    const float* xr = x + (size_t)node * NF;    // rows are 8B-aligned (312B) -> float2
    float a[64];
#pragma unroll
    for (int c = 0; c < 64; c++) a[c] = 0.f;
    for (int k2 = 0; k2 < NF / 2; k2++) {
        float2 xv = ((const float2*)xr)[k2];
        const float* w0 = sW + (2 * k2) * 64;
#pragma unroll
        for (int c = 0; c < 64; c++) a[c] += xv.x * w0[c];
#pragma unroll
        for (int c = 0; c < 64; c++) a[c] += xv.y * w0[64 + c];
    }
    float* orow = out + ((size_t)node << 6);
#pragma unroll
    for (int c = 0; c < 64; c += 4)
        *(float4*)(orow + c) = make_float4(a[c], a[c + 1], a[c + 2], a[c + 3]);
}

// ---------------- second matmul + relu + BN-stats partial accumulation into LDS ps[128]
__device__ __forceinline__ void second_matmul_stats(const float (&a)[64],
                                                    const float* __restrict__ sW2,
                                                    const float* __restrict__ sb2,
                                                    float* __restrict__ orow,
                                                    float* __restrict__ ps) {
#pragma unroll
    for (int cb = 0; cb < 64; cb += 16) {
        float o[16];
#pragma unroll
        for (int j = 0; j < 16; j++) o[j] = sb2[cb + j];
#pragma unroll
        for (int k = 0; k < 64; k++) {
            float ak = a[k];
#pragma unroll
            for (int j = 0; j < 16; j++) o[j] += ak * sW2[k * 64 + cb + j];
        }
#pragma unroll
        for (int j = 0; j < 16; j++) o[j] = fmaxf(o[j], 0.f);
#pragma unroll
        for (int j = 0; j < 16; j += 4)
            *(float4*)(orow + cb + j) = make_float4(o[j], o[j + 1], o[j + 2], o[j + 3]);
#pragma unroll
        for (int j = 0; j < 16; j++) {
            atomicAdd(&ps[cb + j], o[j]);
            atomicAdd(&ps[64 + cb + j], o[j] * o[j]);
        }
    }
}

// ---------------- layer-1 tail: z = relu(relu(acc + b1a) @ w1b + b1b); emits stats partials
__global__ __launch_bounds__(256) void k_mlp_tail(const float* __restrict__ zin,
                                                  const float* __restrict__ b1,
                                                  const float* __restrict__ W2,
                                                  const float* __restrict__ b2,
                                                  float* __restrict__ out,
                                                  float* __restrict__ part) {
    __shared__ float sW2[64 * 64];
    __shared__ float sb1[64], sb2[64];
    __shared__ float ps[128];
    for (int i = threadIdx.x; i < 64 * 64; i += 256) sW2[i] = W2[i];
    if (threadIdx.x < 64) { sb1[threadIdx.x] = b1[threadIdx.x]; sb2[threadIdx.x] = b2[threadIdx.x]; }
    if (threadIdx.x < 128) ps[threadIdx.x] = 0.f;
    __syncthreads();
    int node = blockIdx.x * 256 + threadIdx.x;
    const float* zr = zin + ((size_t)node << 6);
    float a[64];
#pragma unroll
    for (int c = 0; c < 64; c += 4) {
        float4 v = *(const float4*)(zr + c);
        a[c]     = fmaxf(v.x + sb1[c], 0.f);
        a[c + 1] = fmaxf(v.y + sb1[c + 1], 0.f);
        a[c + 2] = fmaxf(v.z + sb1[c + 2], 0.f);
        a[c + 3] = fmaxf(v.w + sb1[c + 3], 0.f);
    }
    second_matmul_stats(a, sW2, sb2, out + ((size_t)node << 6), ps);
    __syncthreads();
    if (threadIdx.x < 128) part[(size_t)blockIdx.x * 128 + threadIdx.x] = ps[threadIdx.x];
}

// ---------------- layers 2-5 MLP: z = relu(relu(acc @ W1 + b1) @ W2 + b2); emits stats partials
__global__ __launch_bounds__(256) void k_mlp_dual(const float* __restrict__ zin,
                                                  const float* __restrict__ W1,
                                                  const float* __restrict__ b1,
                                                  const float* __restrict__ W2,
                                                  const float* __restrict__ b2,
                                                  float* __restrict__ out,
                                                  float* __restrict__ part) {
    __shared__ float sW1[64 * 64];
    __shared__ float sW2[64 * 64];
    __shared__ float sb1[64], sb2[64];
    __shared__ float ps[128];
    for (int i = threadIdx.x; i < 64 * 64; i += 256) { sW1[i] = W1[i]; sW2[i] = W2[i]; }
    if (threadIdx.x < 64) { sb1[threadIdx.x] = b1[threadIdx.x]; sb2[threadIdx.x] = b2[threadIdx.x]; }
    if (threadIdx.x < 128) ps[threadIdx.x] = 0.f;
    __syncthreads();
    int node = blockIdx.x * 256 + threadIdx.x;
    const float* zr = zin + ((size_t)node << 6);
    float a[64];
#pragma unroll
    for (int c = 0; c < 64; c++) a[c] = sb1[c];
    for (int k4 = 0; k4 < 16; k4++) {
        float4 xv = ((const float4*)zr)[k4];
        const float* w = sW1 + k4 * 256;
#pragma unroll
        for (int c = 0; c < 64; c++) a[c] += xv.x * w[c];
#pragma unroll
        for (int c = 0; c < 64; c++) a[c] += xv.y * w[64 + c];
#pragma unroll
        for (int c = 0; c < 64; c++) a[c] += xv.z * w[128 + c];
#pragma unroll
        for (int c = 0; c < 64; c++) a[c] += xv.w * w[192 + c];
    }
#pragma unroll
    for (int c = 0; c < 64; c++) a[c] = fmaxf(a[c], 0.f);
    second_matmul_stats(a, sW2, sb2, out + ((size_t)node << 6), ps);
    __syncthreads();
    if (threadIdx.x < 128) part[(size_t)blockIdx.x * 128 + threadIdx.x] = ps[threadIdx.x];
}

// ---------------- reduce per-block stats partials -> stats[128] (write, no init needed)
__global__ __launch_bounds__(256) void k_bnreduce(const float* __restrict__ part,
                                                  float* __restrict__ stats) {
    int c = threadIdx.x & 63;
    int e = blockIdx.x * 64 + c;   // block 0 -> sums, block 1 -> sumsqs
    int q = threadIdx.x >> 6;
    float s = 0.f;
    for (int b = q; b < NBLK; b += 4) s += part[(size_t)b * 128 + e];
    __shared__ float ls[4][64];
    ls[q][c] = s;
    __syncthreads();
    if (threadIdx.x < 64)
        stats[blockIdx.x * 64 + c] = ls[0][c] + ls[1][c] + ls[2][c] + ls[3][c];
}

// ---------------- final BN apply in place on h (materializes x_seq)
__global__ __launch_bounds__(256) void k_bnapply(float* __restrict__ h,
                                                 const float* __restrict__ stats,
                                                 const float* __restrict__ gamma,
                                                 const float* __restrict__ beta) {
    size_t i = (size_t)blockIdx.x * 256 + threadIdx.x;
    int c0 = (int)(i & 15) * 4;
    const float invN = 1.0f / NNODE;
    float4 v = ((const float4*)h)[i];
    float sc[4], bi[4];
#pragma unroll
    for (int j = 0; j < 4; j++) {
        float mean = stats[c0 + j] * invN;
        float var = stats[64 + c0 + j] * invN - mean * mean;
        float s = gamma[c0 + j] * rsqrtf(var + BN_EPS);
        sc[j] = s;
        bi[j] = beta[c0 + j] - mean * s;
    }
    v.x = v.x * sc[0] + bi[0];
    v.y = v.y * sc[1] + bi[1];
    v.z = v.z * sc[2] + bi[2];
    v.w = v.w * sc[3] + bi[3];
    ((float4*)h)[i] = v;
}

// ---------------- pool + fc + relu + layernorm; one block per graph
__global__ __launch_bounds__(256) void k_final(const float* __restrict__ h,
                                               const float* __restrict__ fcw,
                                               const float* __restrict__ fcb,
                                               const float* __restrict__ lng,
                                               const float* __restrict__ lnb,
                                               float* __restrict__ y) {
    int b = blockIdx.x;
    int q = threadIdx.x >> 6;
    int c = threadIdx.x & 63;
    const float* base = h + (size_t)b * MAXLEN * 64;
    float s = 0.f;
    for (int p = q; p < MAXLEN; p += 4) s += base[p * 64 + c];
    __shared__ float sp[4][64];
    sp[q][c] = s;
    __syncthreads();
    __shared__ float pooled[64];
    if (threadIdx.x < 64) pooled[c] = sp[0][c] + sp[1][c] + sp[2][c] + sp[3][c];
    __syncthreads();
    if (threadIdx.x < 64) {
        float accv = fcb[c];
        for (int k = 0; k < 64; k++) accv += pooled[k] * fcw[k * 64 + c];
        accv = fmaxf(accv, 0.f);
        float t = accv;
        for (int o = 32; o; o >>= 1) t += __shfl_xor(t, o, 64);
        float mu = t * (1.0f / 64.0f);
        float d = accv - mu;
        float t2 = d * d;
        for (int o = 32; o; o >>= 1) t2 += __shfl_xor(t2, o, 64);
        float var = t2 * (1.0f / 64.0f);
        y[(size_t)b * 64 + c] = d * rsqrtf(var + LN_EPS) * lng[c] + lnb[c];
    }
}

extern "C" void kernel_launch(void* const* d_in, const int* in_sizes, int n_in,
                              void* d_out, int out_size, void* d_ws, size_t ws_size,
                              hipStream_t stream) {
    const float* x   = (const float*)d_in[0];
    const int*   ei  = (const int*)d_in[1];
    // d_in[2]=batch, d_in[3]=batch_len, d_in[4]=max_len : structure is fixed, unused
    const float* w1a = (const float*)d_in[5];
    const float* b1a = (const float*)d_in[6];
    const float* w1b = (const float*)d_in[7];
    const float* b1b = (const float*)d_in[8];
    const float* Wa  = (const float*)d_in[9];
    const float* ba  = (const float*)d_in[10];
    const float* Wb  = (const float*)d_in[11];
    const float* bb  = (const float*)d_in[12];
    const float* bng = (const float*)d_in[13];
    const float* bnb = (const float*)d_in[14];
    const float* fcw = (const float*)d_in[15];
    const float* fcb = (const float*)d_in[16];
    const float* lng = (const float*)d_in[17];
    const float* lnb = (const float*)d_in[18];

    float* h   = (float*)d_out;                   // N*64 region == x_seq (identity layout)
    float* y   = h + (size_t)NNODE * 64;          // B*64 region
    float* acc = (float*)d_ws;                    // N*64 accumulator
    float* stats = acc + (size_t)NNODE * 64;      // 5 * 128 raw BN sums
    float* part  = stats + 5 * 128;               // NBLK * 128 per-block partials
    int* deg       = (int*)(part + (size_t)NBLK * 128);
    int* row_start = deg + NNODE;
    int* cursor    = row_start + NNODE;
    int* total     = cursor + NNODE;
    unsigned char* elist = (unsigned char*)(total + 4);  // NEDGE u8 local src ids

    const int NB_NODE = NNODE / 256;              // 2032
    const int NB_VEC  = NNODE * 16 / 256;         // 32512
    const int NB_EDGE = NEDGE / 256;              // 16256
    (void)in_sizes; (void)n_in; (void)out_size; (void)ws_size;

    // ---- build u8 CSR (by dst) once; edges reused by all 5 layers
    k_init<<<NB_NODE, 256, 0, stream>>>(deg, total);
    k_hist<<<NB_EDGE, 256, 0, stream>>>(ei, deg);
    k_scan<<<NB_NODE, 256, 0, stream>>>(deg, row_start, cursor, total);
    k_fill<<<NB_EDGE, 256, 0, stream>>>(ei, cursor, elist);

    // ---- layer 1 (transform-first: t = x@w1a, aggregate in 64-dim space)
    k_gemm78<<<NB_NODE, 256, 0, stream>>>(x, w1a, h);
    k_gather<0><<<NB_VEC, 256, 0, stream>>>(h, elist, row_start, deg, nullptr, nullptr, nullptr, acc);
    k_mlp_tail<<<NB_NODE, 256, 0, stream>>>(acc, b1a, w1b, b1b, h, part);
    k_bnreduce<<<2, 256, 0, stream>>>(part, stats);

    // ---- layers 2..5: gather folds previous layer's BN affine (incl. (1+deg)*bias)
    for (int L = 1; L <= 4; L++) {
        k_gather<1><<<NB_VEC, 256, 0, stream>>>(h, elist, row_start, deg,
                                                stats + (L - 1) * 128,
                                                bng + (size_t)(L - 1) * 64,
                                                bnb + (size_t)(L - 1) * 64, acc);
        k_mlp_dual<<<NB_NODE, 256, 0, stream>>>(acc, Wa + (size_t)(L - 1) * 4096,
                                                ba + (size_t)(L - 1) * 64,
                                                Wb + (size_t)(L - 1) * 4096,
                                                bb + (size_t)(L - 1) * 64, h, part);
        k_bnreduce<<<2, 256, 0, stream>>>(part, stats + L * 128);
    }

    // ---- materialize final post-BN h (x_seq), then pool -> fc -> relu -> layernorm
    k_bnapply<<<NB_VEC, 256, 0, stream>>>(h, stats + 4 * 128, bng + 4 * 64, bnb + 4 * 64);
    k_final<<<NGRAPH, 256, 0, stream>>>(h, fcw, fcb, lng, lnb, y);
}

// Round 4
// 2820.512 us; speedup vs baseline: 2.3310x; 2.3310x over previous
//
#include <hip/hip_runtime.h>

#define NGRAPH 2048
#define MAXLEN 254
#define NNODE 520192      // NGRAPH * MAXLEN
#define NEDGE 4161536     // NNODE * 8
#define NF 78
#define BN_EPS 1e-5f
#define LN_EPS 1e-5f

// ---------------- init: zero degree array, BN stats, total counter
__global__ __launch_bounds__(256) void k_init(int* __restrict__ deg, float* __restrict__ stats,
                                              int* __restrict__ total) {
    int i = blockIdx.x * 256 + threadIdx.x;
    deg[i] = 0;
    if (blockIdx.x == 0) {
        for (int j = threadIdx.x; j < 5 * 128; j += 256) stats[j] = 0.f;
        if (threadIdx.x == 0) *total = 0;
    }
}

// ---------------- in-degree histogram
__global__ __launch_bounds__(256) void k_hist(const int* __restrict__ ei, int* __restrict__ deg) {
    int e = blockIdx.x * 256 + threadIdx.x;  // NEDGE threads exactly
    atomicAdd(&deg[ei[NEDGE + e]], 1);
}

// ---------------- row offsets: wave-level exclusive scan + one atomic per wave
__global__ __launch_bounds__(256) void k_scan(const int* __restrict__ deg,
                                              int* __restrict__ row_start,
                                              int* __restrict__ cursor, int* __restrict__ total) {
    int i = blockIdx.x * 256 + threadIdx.x;
    int d = deg[i];
    int lane = threadIdx.x & 63;
    int v = d;
#pragma unroll
    for (int o = 1; o < 64; o <<= 1) {
        int t = __shfl_up(v, o, 64);
        if (lane >= o) v += t;
    }
    int wsum = __shfl(v, 63, 64);
    int base = 0;
    if (lane == 63) base = atomicAdd(total, wsum);
    base = __shfl(base, 63, 64);
    int start = base + v - d;
    row_start[i] = start;
    cursor[i] = start;
}

// ---------------- scatter LOCAL src ids (u8) into per-dst contiguous lists
__global__ __launch_bounds__(256) void k_fill(const int* __restrict__ ei, int* __restrict__ cursor,
                                              unsigned char* __restrict__ elist) {
    int e = blockIdx.x * 256 + threadIdx.x;
    int s = ei[e];
    int d = ei[NEDGE + e];
    int g = d / MAXLEN;                       // same graph as src by construction
    int p = atomicAdd(&cursor[d], 1);
    elist[p] = (unsigned char)(s - g * MAXLEN);
}

// ---------------- CSR gather: acc[i] = z[i] + sum_{j->i} z[j]; optionally fold BN affine:
//   acc = agg_z * sc + (1+deg) * bi   where sc/bi derive from raw stats (sum, sumsq)
template <int FOLD>
__global__ __launch_bounds__(256) void k_gather(const float* __restrict__ h,
                                                const unsigned char* __restrict__ elist,
                                                const int* __restrict__ row_start,
                                                const int* __restrict__ deg,
                                                const float* __restrict__ stats,
                                                const float* __restrict__ gamma,
                                                const float* __restrict__ beta,
                                                float* __restrict__ acc) {
    size_t t = (size_t)blockIdx.x * 256 + threadIdx.x;  // NNODE*16 threads
    int node = (int)(t >> 4);
    int g4 = (int)(t & 15) * 4;
    int rs = row_start[node];
    int dg = deg[node];
    int base = (node / MAXLEN) * MAXLEN;                // graph base node id
    const float4 h0 = *(const float4*)(h + ((size_t)node << 6) + g4);
    float a0 = h0.x, a1 = h0.y, a2 = h0.z, a3 = h0.w;
    for (int e = 0; e < dg; e++) {
        int s = base + elist[rs + e];
        float4 v = *(const float4*)(h + ((size_t)s << 6) + g4);
        a0 += v.x; a1 += v.y; a2 += v.z; a3 += v.w;
    }
    if (FOLD) {
        const float invN = 1.0f / NNODE;
        float k = (float)(1 + dg);
        float r[4] = {a0, a1, a2, a3};
#pragma unroll
        for (int j = 0; j < 4; j++) {
            float mean = stats[g4 + j] * invN;
            float var = stats[64 + g4 + j] * invN - mean * mean;
            float sc = gamma[g4 + j] * rsqrtf(var + BN_EPS);
            float bi = beta[g4 + j] - mean * sc;
            r[j] = r[j] * sc + k * bi;
        }
        a0 = r[0]; a1 = r[1]; a2 = r[2]; a3 = r[3];
    }
    *(float4*)(acc + ((size_t)node << 6) + g4) = make_float4(a0, a1, a2, a3);
}

// ---------------- layer-1 first GEMM: t = x @ w1a (N x 78 @ 78 x 64)
__global__ __launch_bounds__(256) void k_gemm78(const float* __restrict__ x,
                                                const float* __restrict__ W,
                                                float* __restrict__ out) {
    __shared__ float sW[NF * 64];
    for (int i = threadIdx.x; i < NF * 64; i += 256) sW[i] = W[i];
    __syncthreads();
    int node = blockIdx.x * 256 + threadIdx.x;  // N divisible by 256
    const float* xr = x + (size_t)node * NF;    // rows are 8B-aligned (312B) -> float2
    float a[64];
#pragma unroll
    for (int c = 0; c < 64; c++) a[c] = 0.f;
    for (int k2 = 0; k2 < NF / 2; k2++) {
        float2 xv = ((const float2*)xr)[k2];
        const float* w0 = sW + (2 * k2) * 64;
#pragma unroll
        for (int c = 0; c < 64; c++) a[c] += xv.x * w0[c];
#pragma unroll
        for (int c = 0; c < 64; c++) a[c] += xv.y * w0[64 + c];
    }
    float* orow = out + ((size_t)node << 6);
#pragma unroll
    for (int c = 0; c < 64; c += 4)
        *(float4*)(orow + c) = make_float4(a[c], a[c + 1], a[c + 2], a[c + 3]);
}

// ---------------- shared second matmul: out = relu(a @ W2 + b2)
__device__ __forceinline__ void second_matmul(const float (&a)[64], const float* __restrict__ sW2,
                                              const float* __restrict__ sb2,
                                              float* __restrict__ orow) {
#pragma unroll
    for (int cb = 0; cb < 64; cb += 16) {
        float o[16];
#pragma unroll
        for (int j = 0; j < 16; j++) o[j] = sb2[cb + j];
#pragma unroll
        for (int k = 0; k < 64; k++) {
            float ak = a[k];
#pragma unroll
            for (int j = 0; j < 16; j++) o[j] += ak * sW2[k * 64 + cb + j];
        }
#pragma unroll
        for (int j = 0; j < 16; j += 4)
            *(float4*)(orow + cb + j) =
                make_float4(fmaxf(o[j], 0.f), fmaxf(o[j + 1], 0.f),
                            fmaxf(o[j + 2], 0.f), fmaxf(o[j + 3], 0.f));
    }
}

// ---------------- layer-1 tail: z = relu(relu(acc + b1a) @ w1b + b1b)
__global__ __launch_bounds__(256) void k_mlp_tail(const float* __restrict__ zin,
                                                  const float* __restrict__ b1,
                                                  const float* __restrict__ W2,
                                                  const float* __restrict__ b2,
                                                  float* __restrict__ out) {
    __shared__ float sW2[64 * 64];
    __shared__ float sb1[64], sb2[64];
    for (int i = threadIdx.x; i < 64 * 64; i += 256) sW2[i] = W2[i];
    if (threadIdx.x < 64) { sb1[threadIdx.x] = b1[threadIdx.x]; sb2[threadIdx.x] = b2[threadIdx.x]; }
    __syncthreads();
    int node = blockIdx.x * 256 + threadIdx.x;
    const float* zr = zin + ((size_t)node << 6);
    float a[64];
#pragma unroll
    for (int c = 0; c < 64; c += 4) {
        float4 v = *(const float4*)(zr + c);
        a[c]     = fmaxf(v.x + sb1[c], 0.f);
        a[c + 1] = fmaxf(v.y + sb1[c + 1], 0.f);
        a[c + 2] = fmaxf(v.z + sb1[c + 2], 0.f);
        a[c + 3] = fmaxf(v.w + sb1[c + 3], 0.f);
    }
    second_matmul(a, sW2, sb2, out + ((size_t)node << 6));
}

// ---------------- layers 2-5 MLP: z = relu(relu(acc @ W1 + b1) @ W2 + b2)
__global__ __launch_bounds__(256) void k_mlp_dual(const float* __restrict__ zin,
                                                  const float* __restrict__ W1,
                                                  const float* __restrict__ b1,
                                                  const float* __restrict__ W2,
                                                  const float* __restrict__ b2,
                                                  float* __restrict__ out) {
    __shared__ float sW1[64 * 64];
    __shared__ float sW2[64 * 64];
    __shared__ float sb1[64], sb2[64];
    for (int i = threadIdx.x; i < 64 * 64; i += 256) { sW1[i] = W1[i]; sW2[i] = W2[i]; }
    if (threadIdx.x < 64) { sb1[threadIdx.x] = b1[threadIdx.x]; sb2[threadIdx.x] = b2[threadIdx.x]; }
    __syncthreads();
    int node = blockIdx.x * 256 + threadIdx.x;
    const float* zr = zin + ((size_t)node << 6);
    float a[64];
#pragma unroll
    for (int c = 0; c < 64; c++) a[c] = sb1[c];
    for (int k4 = 0; k4 < 16; k4++) {
        float4 xv = ((const float4*)zr)[k4];
        const float* w = sW1 + k4 * 256;
#pragma unroll
        for (int c = 0; c < 64; c++) a[c] += xv.x * w[c];
#pragma unroll
        for (int c = 0; c < 64; c++) a[c] += xv.y * w[64 + c];
#pragma unroll
        for (int c = 0; c < 64; c++) a[c] += xv.z * w[128 + c];
#pragma unroll
        for (int c = 0; c < 64; c++) a[c] += xv.w * w[192 + c];
    }
#pragma unroll
    for (int c = 0; c < 64; c++) a[c] = fmaxf(a[c], 0.f);
    second_matmul(a, sW2, sb2, out + ((size_t)node << 6));
}

// ---------------- BN stats sweep: per-channel sum/sumsq; register-private partials,
// 8 LDS atomics per thread, 128 global atomics per block
__global__ __launch_bounds__(256) void k_bnstats(const float* __restrict__ h,
                                                 float* __restrict__ stats) {
    __shared__ float ss[128];
    if (threadIdx.x < 128) ss[threadIdx.x] = 0.f;
    __syncthreads();
    int tid = blockIdx.x * 256 + threadIdx.x;  // 65536 threads; stride keeps channel fixed
    int c4 = (tid & 15) * 4;
    float s0 = 0, s1 = 0, s2 = 0, s3 = 0, q0 = 0, q1 = 0, q2 = 0, q3 = 0;
    const float4* p = (const float4*)h;
    for (size_t i = tid; i < (size_t)NNODE * 16; i += 65536) {
        float4 v = p[i];
        s0 += v.x; q0 += v.x * v.x;
        s1 += v.y; q1 += v.y * v.y;
        s2 += v.z; q2 += v.z * v.z;
        s3 += v.w; q3 += v.w * v.w;
    }
    atomicAdd(&ss[c4], s0);      atomicAdd(&ss[c4 + 1], s1);
    atomicAdd(&ss[c4 + 2], s2);  atomicAdd(&ss[c4 + 3], s3);
    atomicAdd(&ss[64 + c4], q0); atomicAdd(&ss[64 + c4 + 1], q1);
    atomicAdd(&ss[64 + c4 + 2], q2); atomicAdd(&ss[64 + c4 + 3], q3);
    __syncthreads();
    if (threadIdx.x < 128) atomicAdd(&stats[threadIdx.x], ss[threadIdx.x]);
}

// ---------------- final BN apply in place on h (materializes x_seq)
__global__ __launch_bounds__(256) void k_bnapply(float* __restrict__ h,
                                                 const float* __restrict__ stats,
                                                 const float* __restrict__ gamma,
                                                 const float* __restrict__ beta) {
    size_t i = (size_t)blockIdx.x * 256 + threadIdx.x;
    int c0 = (int)(i & 15) * 4;
    const float invN = 1.0f / NNODE;
    float4 v = ((const float4*)h)[i];
    float sc[4], bi[4];
#pragma unroll
    for (int j = 0; j < 4; j++) {
        float mean = stats[c0 + j] * invN;
        float var = stats[64 + c0 + j] * invN - mean * mean;
        float s = gamma[c0 + j] * rsqrtf(var + BN_EPS);
        sc[j] = s;
        bi[j] = beta[c0 + j] - mean * s;
    }
    v.x = v.x * sc[0] + bi[0];
    v.y = v.y * sc[1] + bi[1];
    v.z = v.z * sc[2] + bi[2];
    v.w = v.w * sc[3] + bi[3];
    ((float4*)h)[i] = v;
}

// ---------------- pool + fc + relu + layernorm; one block per graph
__global__ __launch_bounds__(256) void k_final(const float* __restrict__ h,
                                               const float* __restrict__ fcw,
                                               const float* __restrict__ fcb,
                                               const float* __restrict__ lng,
                                               const float* __restrict__ lnb,
                                               float* __restrict__ y) {
    int b = blockIdx.x;
    int q = threadIdx.x >> 6;
    int c = threadIdx.x & 63;
    const float* base = h + (size_t)b * MAXLEN * 64;
    float s = 0.f;
    for (int p = q; p < MAXLEN; p += 4) s += base[p * 64 + c];
    __shared__ float sp[4][64];
    sp[q][c] = s;
    __syncthreads();
    __shared__ float pooled[64];
    if (threadIdx.x < 64) pooled[c] = sp[0][c] + sp[1][c] + sp[2][c] + sp[3][c];
    __syncthreads();
    if (threadIdx.x < 64) {
        float accv = fcb[c];
        for (int k = 0; k < 64; k++) accv += pooled[k] * fcw[k * 64 + c];
        accv = fmaxf(accv, 0.f);
        float t = accv;
        for (int o = 32; o; o >>= 1) t += __shfl_xor(t, o, 64);
        float mu = t * (1.0f / 64.0f);
        float d = accv - mu;
        float t2 = d * d;
        for (int o = 32; o; o >>= 1) t2 += __shfl_xor(t2, o, 64);
        float var = t2 * (1.0f / 64.0f);
        y[(size_t)b * 64 + c] = d * rsqrtf(var + LN_EPS) * lng[c] + lnb[c];
    }
}

extern "C" void kernel_launch(void* const* d_in, const int* in_sizes, int n_in,
                              void* d_out, int out_size, void* d_ws, size_t ws_size,
                              hipStream_t stream) {
    const float* x   = (const float*)d_in[0];
    const int*   ei  = (const int*)d_in[1];
    // d_in[2]=batch, d_in[3]=batch_len, d_in[4]=max_len : structure is fixed, unused
    const float* w1a = (const float*)d_in[5];
    const float* b1a = (const float*)d_in[6];
    const float* w1b = (const float*)d_in[7];
    const float* b1b = (const float*)d_in[8];
    const float* Wa  = (const float*)d_in[9];
    const float* ba  = (const float*)d_in[10];
    const float* Wb  = (const float*)d_in[11];
    const float* bb  = (const float*)d_in[12];
    const float* bng = (const float*)d_in[13];
    const float* bnb = (const float*)d_in[14];
    const float* fcw = (const float*)d_in[15];
    const float* fcb = (const float*)d_in[16];
    const float* lng = (const float*)d_in[17];
    const float* lnb = (const float*)d_in[18];

    float* h   = (float*)d_out;                   // N*64 region == x_seq (identity layout)
    float* y   = h + (size_t)NNODE * 64;          // B*64 region
    float* acc = (float*)d_ws;                    // N*64 accumulator
    float* stats = acc + (size_t)NNODE * 64;      // 5 * 128 raw BN sums
    int* deg       = (int*)(stats + 5 * 128);
    int* row_start = deg + NNODE;
    int* cursor    = row_start + NNODE;
    int* total     = cursor + NNODE;
    unsigned char* elist = (unsigned char*)(total + 4);  // NEDGE u8 local src ids

    const int NB_NODE = NNODE / 256;              // 2032
    const int NB_VEC  = NNODE * 16 / 256;         // 32512
    const int NB_EDGE = NEDGE / 256;              // 16256
    (void)in_sizes; (void)n_in; (void)out_size; (void)ws_size;

    // ---- build u8 CSR (by dst) once; edges reused by all 5 layers
    k_init<<<NB_NODE, 256, 0, stream>>>(deg, stats, total);
    k_hist<<<NB_EDGE, 256, 0, stream>>>(ei, deg);
    k_scan<<<NB_NODE, 256, 0, stream>>>(deg, row_start, cursor, total);
    k_fill<<<NB_EDGE, 256, 0, stream>>>(ei, cursor, elist);

    // ---- layer 1 (transform-first: t = x@w1a, aggregate in 64-dim space)
    k_gemm78<<<NB_NODE, 256, 0, stream>>>(x, w1a, h);
    k_gather<0><<<NB_VEC, 256, 0, stream>>>(h, elist, row_start, deg, nullptr, nullptr, nullptr, acc);
    k_mlp_tail<<<NB_NODE, 256, 0, stream>>>(acc, b1a, w1b, b1b, h);
    k_bnstats<<<256, 256, 0, stream>>>(h, stats);

    // ---- layers 2..5: gather folds previous layer's BN affine (incl. (1+deg)*bias)
    for (int L = 1; L <= 4; L++) {
        k_gather<1><<<NB_VEC, 256, 0, stream>>>(h, elist, row_start, deg,
                                                stats + (L - 1) * 128,
                                                bng + (size_t)(L - 1) * 64,
                                                bnb + (size_t)(L - 1) * 64, acc);
        k_mlp_dual<<<NB_NODE, 256, 0, stream>>>(acc, Wa + (size_t)(L - 1) * 4096,
                                                ba + (size_t)(L - 1) * 64,
                                                Wb + (size_t)(L - 1) * 4096,
                                                bb + (size_t)(L - 1) * 64, h);
        k_bnstats<<<256, 256, 0, stream>>>(h, stats + L * 128);
    }

    // ---- materialize final post-BN h (x_seq), then pool -> fc -> relu -> layernorm
    k_bnapply<<<NB_VEC, 256, 0, stream>>>(h, stats + 4 * 128, bng + 4 * 64, bnb + 4 * 64);
    k_final<<<NGRAPH, 256, 0, stream>>>(h, fcw, fcb, lng, lnb, y);
}